// Round 1
// baseline (1095.148 us; speedup 1.0000x reference)
//
#include <hip/hip_runtime.h>

#define N_NODES 100000
#define IN_DIM 128
#define HID 64
#define NUM_GRAPHS 2048

// ---------------- degree / CSR build ----------------

__global__ void count_deg(const int* __restrict__ dst, int* __restrict__ deg, int E) {
    int e = blockIdx.x * blockDim.x + threadIdx.x;
    if (e < E) atomicAdd(&deg[dst[e]], 1);
}

__global__ void compute_dis(const int* __restrict__ deg, float* __restrict__ dis, int n) {
    int i = blockIdx.x * blockDim.x + threadIdx.x;
    if (i < n) dis[i] = rsqrtf((float)(deg[i] + 1));   // +1 self-loop
}

// scan1: per-block (1024 elements) inclusive scan of counts -> row_ptr[i+1] (local), block sums
__global__ void scan1(const int* __restrict__ counts, int* __restrict__ row_ptr1,
                      int* __restrict__ bsum, int n) {
    __shared__ int s[256];
    int t = threadIdx.x;
    int base = blockIdx.x * 1024 + t * 4;
    int v[4];
#pragma unroll
    for (int i = 0; i < 4; i++) v[i] = (base + i < n) ? counts[base + i] : 0;
    int tsum = v[0] + v[1] + v[2] + v[3];
    s[t] = tsum;
    __syncthreads();
    for (int off = 1; off < 256; off <<= 1) {
        int tv = (t >= off) ? s[t - off] : 0;
        __syncthreads();
        s[t] += tv;
        __syncthreads();
    }
    int excl = s[t] - tsum;
    if (t == 255) bsum[blockIdx.x] = s[255];
    int run = excl;
#pragma unroll
    for (int i = 0; i < 4; i++) {
        run += v[i];
        if (base + i < n) row_ptr1[base + i] = run;
    }
}

// scan2: exclusive scan of block sums (nb <= 128)
__global__ void scan2(const int* __restrict__ bsum, int* __restrict__ boff, int nb) {
    __shared__ int s[128];
    int t = threadIdx.x;
    int v = (t < nb) ? bsum[t] : 0;
    s[t] = v;
    __syncthreads();
    for (int off = 1; off < 128; off <<= 1) {
        int tv = (t >= off) ? s[t - off] : 0;
        __syncthreads();
        s[t] += tv;
        __syncthreads();
    }
    if (t < nb) boff[t] = s[t] - v;
}

// scan3: add block offsets, finalize row_ptr and the scatter-fill cursors
__global__ void scan3(const int* __restrict__ counts, int* __restrict__ row_ptr,
                      int* __restrict__ row_fill, const int* __restrict__ boff, int n) {
    int i = blockIdx.x * blockDim.x + threadIdx.x;
    if (i == 0) row_ptr[0] = 0;
    if (i < n) {
        int rp = row_ptr[i + 1] + boff[i >> 10];
        row_ptr[i + 1] = rp;
        row_fill[i] = rp - counts[i];
    }
}

__global__ void scatter_edges(const int* __restrict__ src, const int* __restrict__ dst,
                              const float* __restrict__ dis, int* __restrict__ row_fill,
                              int* __restrict__ col_idx, float* __restrict__ enorm, int E) {
    int e = blockIdx.x * blockDim.x + threadIdx.x;
    if (e < E) {
        int s = src[e], d = dst[e];
        int pos = atomicAdd(&row_fill[d], 1);
        col_idx[pos] = s;
        enorm[pos] = dis[s] * dis[d];
    }
}

// ---------------- per-layer compute ----------------

__device__ __forceinline__ float bcast(float v, int lane) {
    return __uint_as_float(__builtin_amdgcn_readlane(__float_as_uint(v), lane));
}

// out[row][lane] = sum_k X[row][k] * W[k][lane]; one wave per row, W staged in LDS.
template <int K>
__global__ __launch_bounds__(256) void gemm_rows(const float* __restrict__ X,
                                                 const float* __restrict__ W,
                                                 float* __restrict__ out, int n) {
    __shared__ float Wl[K * HID];
    for (int i = threadIdx.x; i < K * HID; i += blockDim.x) Wl[i] = W[i];
    __syncthreads();
    int wave = threadIdx.x >> 6, lane = threadIdx.x & 63;
    int wpb = blockDim.x >> 6;
    int stride = gridDim.x * wpb;
    for (int row = blockIdx.x * wpb + wave; row < n; row += stride) {
        const float* xr = X + (size_t)row * K;
        float acc = 0.f;
        float xv0 = xr[lane];
        if constexpr (K == 128) {
            float xv1 = xr[lane + 64];
#pragma unroll
            for (int k = 0; k < 64; k++) acc += bcast(xv0, k) * Wl[k * HID + lane];
#pragma unroll
            for (int k = 0; k < 64; k++) acc += bcast(xv1, k) * Wl[(k + 64) * HID + lane];
        } else {
#pragma unroll
            for (int k = 0; k < 64; k++) acc += bcast(xv0, k) * Wl[k * HID + lane];
        }
        out[(size_t)row * HID + lane] = acc;
    }
}

// h_out[row][lane] = relu( (1/deg_row)*tmp[row][lane] + sum_e norm_e*tmp[col_e][lane] + b[lane] )
__global__ __launch_bounds__(256) void aggregate(const float* __restrict__ tmp,
                                                 const float* __restrict__ dis,
                                                 const int* __restrict__ row_ptr,
                                                 const int* __restrict__ col_idx,
                                                 const float* __restrict__ enorm,
                                                 const float* __restrict__ bias,
                                                 float* __restrict__ out, int n) {
    int wave = threadIdx.x >> 6, lane = threadIdx.x & 63;
    int wpb = blockDim.x >> 6;
    int stride = gridDim.x * wpb;
    for (int row = blockIdx.x * wpb + wave; row < n; row += stride) {
        float d = dis[row];
        float acc = d * d * tmp[(size_t)row * HID + lane];  // self-loop
        int s = row_ptr[row], e = row_ptr[row + 1];
        for (int t = s; t < e; t++) {
            int c = col_idx[t];
            acc += enorm[t] * tmp[(size_t)c * HID + lane];
        }
        acc += bias[lane];
        out[(size_t)row * HID + lane] = fmaxf(acc, 0.f);
    }
}

// one wave per graph: mean+max pool over its node range (batch is sorted), fused output dot
__global__ void pool_kernel(const float* __restrict__ h, const int* __restrict__ batch,
                            const float* __restrict__ Wout, const float* __restrict__ bout,
                            float* __restrict__ d_out, int n) {
    int g = blockIdx.x;
    int j = threadIdx.x;  // 64 threads
    // lower_bound(batch, g), lower_bound(batch, g+1)
    int lo = 0, hi = n;
    while (lo < hi) { int mid = (lo + hi) >> 1; if (batch[mid] < g) lo = mid + 1; else hi = mid; }
    int start = lo;
    hi = n;
    while (lo < hi) { int mid = (lo + hi) >> 1; if (batch[mid] < g + 1) lo = mid + 1; else hi = mid; }
    int end = lo;

    float sum = 0.f, mx = 0.f;  // h >= 0 post-relu, and empty graphs -> 0 per reference
    for (int i = start; i < end; i++) {
        float v = h[(size_t)i * HID + j];
        sum += v;
        mx = fmaxf(mx, v);
    }
    float cnt = (float)(end - start);
    float mean = sum / fmaxf(cnt, 1.f);

    float* pooled = d_out + NUM_GRAPHS;
    pooled[(size_t)g * (2 * HID) + j] = mean;
    pooled[(size_t)g * (2 * HID) + HID + j] = mx;

    float c = mean * Wout[j] + mx * Wout[HID + j];
#pragma unroll
    for (int off = 32; off; off >>= 1) c += __shfl_down(c, off);
    if (j == 0) d_out[g] = c + bout[0];
}

// ---------------- launch ----------------

extern "C" void kernel_launch(void* const* d_in, const int* in_sizes, int n_in,
                              void* d_out, int out_size, void* d_ws, size_t ws_size,
                              hipStream_t stream) {
    const float* x    = (const float*)d_in[0];
    const int*   edge = (const int*)d_in[1];
    const int*   batch= (const int*)d_in[2];
    const float* W1 = (const float*)d_in[3];  const float* b1 = (const float*)d_in[4];
    const float* W2 = (const float*)d_in[5];  const float* b2 = (const float*)d_in[6];
    const float* W3 = (const float*)d_in[7];  const float* b3 = (const float*)d_in[8];
    const float* W4 = (const float*)d_in[9];  const float* b4 = (const float*)d_in[10];
    const float* Wout = (const float*)d_in[11]; const float* bout = (const float*)d_in[12];
    float* out = (float*)d_out;

    const int N = N_NODES;
    const int E = in_sizes[1] / 2;
    const int* src = edge;
    const int* dst = edge + E;

    // bump allocator over d_ws (re-poisoned each call; everything rebuilt each call)
    char* p = (char*)d_ws;
    auto alloc = [&](size_t bytes) -> char* {
        char* r = p;
        p += (bytes + 255) & ~(size_t)255;
        return r;
    };
    int*   deg      = (int*)alloc((size_t)N * 4);
    int*   row_ptr  = (int*)alloc((size_t)(N + 1) * 4);
    int*   row_fill = (int*)alloc((size_t)N * 4);
    int*   col_idx  = (int*)alloc((size_t)E * 4);
    float* enorm    = (float*)alloc((size_t)E * 4);
    float* dis      = (float*)alloc((size_t)N * 4);
    int*   bsum     = (int*)alloc(128 * 4);
    int*   boff     = (int*)alloc(128 * 4);
    float* tmp      = (float*)alloc((size_t)N * HID * 4);
    float* hA       = (float*)alloc((size_t)N * HID * 4);

    hipMemsetAsync(deg, 0, (size_t)N * 4, stream);
    count_deg<<<(E + 255) / 256, 256, 0, stream>>>(dst, deg, E);
    compute_dis<<<(N + 255) / 256, 256, 0, stream>>>(deg, dis, N);

    int nb = (N + 1023) / 1024;  // 98
    scan1<<<nb, 256, 0, stream>>>(deg, row_ptr + 1, bsum, N);
    scan2<<<1, 128, 0, stream>>>(bsum, boff, nb);
    scan3<<<(N + 255) / 256, 256, 0, stream>>>(deg, row_ptr, row_fill, boff, N);
    scatter_edges<<<(E + 255) / 256, 256, 0, stream>>>(src, dst, dis, row_fill, col_idx, enorm, E);

    const int GEMM_BLOCKS = 1024;  // 4096 waves, ~24 rows each; W staged once per block
    const int AGG_BLOCKS = 2048;   // 8192 waves for load balance over variable degree

    // layer 1: x[N,128] @ W1 -> tmp; aggregate -> hA
    gemm_rows<IN_DIM><<<GEMM_BLOCKS, 256, 0, stream>>>(x, W1, tmp, N);
    aggregate<<<AGG_BLOCKS, 256, 0, stream>>>(tmp, dis, row_ptr, col_idx, enorm, b1, hA, N);
    // layers 2-4: ping-pong hA <-> tmp (aggregate may overwrite its gemm input's source)
    gemm_rows<HID><<<GEMM_BLOCKS, 256, 0, stream>>>(hA, W2, tmp, N);
    aggregate<<<AGG_BLOCKS, 256, 0, stream>>>(tmp, dis, row_ptr, col_idx, enorm, b2, hA, N);
    gemm_rows<HID><<<GEMM_BLOCKS, 256, 0, stream>>>(hA, W3, tmp, N);
    aggregate<<<AGG_BLOCKS, 256, 0, stream>>>(tmp, dis, row_ptr, col_idx, enorm, b3, hA, N);
    gemm_rows<HID><<<GEMM_BLOCKS, 256, 0, stream>>>(hA, W4, tmp, N);
    aggregate<<<AGG_BLOCKS, 256, 0, stream>>>(tmp, dis, row_ptr, col_idx, enorm, b4, hA, N);

    pool_kernel<<<NUM_GRAPHS, 64, 0, stream>>>(hA, batch, Wout, bout, out, N);
}

// Round 2
// 666.992 us; speedup vs baseline: 1.6419x; 1.6419x over previous
//
#include <hip/hip_runtime.h>

#define N_NODES 100000
#define IN_DIM 128
#define HID 64
#define NUM_GRAPHS 2048
#define CNE_MAX (1600000 + 3 * N_NODES)   // sum of per-row pad-to-4 degrees upper bound

// ---------------- degree / CSR build ----------------

__global__ void count_deg(const int* __restrict__ dst, int* __restrict__ deg, int E) {
    int e = blockIdx.x * blockDim.x + threadIdx.x;
    if (e < E) atomicAdd(&deg[dst[e]], 1);
}

__global__ void compute_dis(const int* __restrict__ deg, float* __restrict__ dis, int n) {
    int i = blockIdx.x * blockDim.x + threadIdx.x;
    if (i < n) dis[i] = rsqrtf((float)(deg[i] + 1));   // +1 self-loop
}

// scan1: per-block (1024 elems) inclusive scan of PADDED degree -> row_ptr[i+1] (local), block sums
__global__ void scan1(const int* __restrict__ counts, int* __restrict__ row_ptr1,
                      int* __restrict__ bsum, int n) {
    __shared__ int s[256];
    int t = threadIdx.x;
    int base = blockIdx.x * 1024 + t * 4;
    int v[4];
#pragma unroll
    for (int i = 0; i < 4; i++) {
        int c = (base + i < n) ? counts[base + i] : 0;
        v[i] = (c + 3) & ~3;                            // pad row segment to multiple of 4
    }
    int tsum = v[0] + v[1] + v[2] + v[3];
    s[t] = tsum;
    __syncthreads();
    for (int off = 1; off < 256; off <<= 1) {
        int tv = (t >= off) ? s[t - off] : 0;
        __syncthreads();
        s[t] += tv;
        __syncthreads();
    }
    int excl = s[t] - tsum;
    if (t == 255) bsum[blockIdx.x] = s[255];
    int run = excl;
#pragma unroll
    for (int i = 0; i < 4; i++) {
        run += v[i];
        if (base + i < n) row_ptr1[base + i] = run;
    }
}

// scan2: exclusive scan of block sums (nb <= 128)
__global__ void scan2(const int* __restrict__ bsum, int* __restrict__ boff, int nb) {
    __shared__ int s[128];
    int t = threadIdx.x;
    int v = (t < nb) ? bsum[t] : 0;
    s[t] = v;
    __syncthreads();
    for (int off = 1; off < 128; off <<= 1) {
        int tv = (t >= off) ? s[t - off] : 0;
        __syncthreads();
        s[t] += tv;
        __syncthreads();
    }
    if (t < nb) boff[t] = s[t] - v;
}

// scan3: add block offsets, finalize row_ptr and scatter-fill cursors (fill starts at segment start)
__global__ void scan3(const int* __restrict__ counts, int* __restrict__ row_ptr,
                      int* __restrict__ row_fill, const int* __restrict__ boff, int n) {
    int i = blockIdx.x * blockDim.x + threadIdx.x;
    if (i == 0) row_ptr[0] = 0;
    if (i < n) {
        int rp = row_ptr[i + 1] + boff[i >> 10];
        row_ptr[i + 1] = rp;
        int pdeg = (counts[i] + 3) & ~3;
        row_fill[i] = rp - pdeg;
    }
}

__global__ void scatter_edges(const int* __restrict__ src, const int* __restrict__ dst,
                              const float* __restrict__ dis, int* __restrict__ row_fill,
                              int2* __restrict__ cne, int E) {
    int e = blockIdx.x * blockDim.x + threadIdx.x;
    if (e < E) {
        int s = src[e], d = dst[e];
        int pos = atomicAdd(&row_fill[d], 1);
        cne[pos] = make_int2(s, __float_as_int(dis[s] * dis[d]));
    }
}

// ---------------- per-layer compute ----------------

__device__ __forceinline__ float bcast(float v, int lane) {
    return __uint_as_float(__builtin_amdgcn_readlane(__float_as_uint(v), lane));
}

// out[row][lane] = sum_k X[row][k] * W[k][lane]; one wave per row, W held in REGISTERS
// (lane l keeps column l of W: w[k] = W[k][l]), loaded once per wave lifetime.
template <int K>
__global__ __launch_bounds__(256) void gemm_rows(const float* __restrict__ X,
                                                 const float* __restrict__ W,
                                                 float* __restrict__ out, int n) {
    int wave = threadIdx.x >> 6, lane = threadIdx.x & 63;
    float w[K];
#pragma unroll
    for (int k = 0; k < K; k++) w[k] = W[k * HID + lane];
    int wpb = blockDim.x >> 6;
    int stride = gridDim.x * wpb;
    for (int row = blockIdx.x * wpb + wave; row < n; row += stride) {
        const float* xr = X + (size_t)row * K;
        float acc0 = 0.f, acc1 = 0.f;
        float xv0 = xr[lane];
        if constexpr (K == 128) {
            float xv1 = xr[lane + 64];
#pragma unroll
            for (int k = 0; k < 64; k += 2) {
                acc0 += bcast(xv0, k) * w[k];
                acc1 += bcast(xv0, k + 1) * w[k + 1];
            }
#pragma unroll
            for (int k = 0; k < 64; k += 2) {
                acc0 += bcast(xv1, k) * w[k + 64];
                acc1 += bcast(xv1, k + 1) * w[k + 65];
            }
        } else {
#pragma unroll
            for (int k = 0; k < 64; k += 2) {
                acc0 += bcast(xv0, k) * w[k];
                acc1 += bcast(xv0, k + 1) * w[k + 1];
            }
        }
        out[(size_t)row * HID + lane] = acc0 + acc1;
    }
}

// h_out[row][lane] = relu( dis^2*tmp[row][lane] + sum_e norm_e*tmp[col_e][lane] + b[lane] )
// Row segments are padded to multiples of 4 (pad entries: col=0, norm=0).
// Software-pipelined depth-2, 4-wide: 8 row-gathers in flight per wave.
__global__ __launch_bounds__(256) void aggregate(const float* __restrict__ tmp,
                                                 const float* __restrict__ dis,
                                                 const int* __restrict__ row_ptr,
                                                 const int2* __restrict__ cne,
                                                 const float* __restrict__ bias,
                                                 float* __restrict__ out, int n) {
    int wave = threadIdx.x >> 6, lane = threadIdx.x & 63;
    int wpb = blockDim.x >> 6;
    int stride = gridDim.x * wpb;
    for (int row = blockIdx.x * wpb + wave; row < n; row += stride) {
        float d = dis[row];
        float acc0 = d * d * tmp[(size_t)row * HID + lane];   // self-loop
        float acc1 = 0.f, acc2 = 0.f, acc3 = 0.f;
        int s = row_ptr[row], e = row_ptr[row + 1];
        if (s < e) {
            int2 c0 = cne[s], c1 = cne[s + 1], c2 = cne[s + 2], c3 = cne[s + 3];
            float v0 = tmp[(size_t)c0.x * HID + lane];
            float v1 = tmp[(size_t)c1.x * HID + lane];
            float v2 = tmp[(size_t)c2.x * HID + lane];
            float v3 = tmp[(size_t)c3.x * HID + lane];
            for (int t = s + 4; t < e; t += 4) {
                int2 d0 = cne[t], d1 = cne[t + 1], d2 = cne[t + 2], d3 = cne[t + 3];
                float u0 = tmp[(size_t)d0.x * HID + lane];
                float u1 = tmp[(size_t)d1.x * HID + lane];
                float u2 = tmp[(size_t)d2.x * HID + lane];
                float u3 = tmp[(size_t)d3.x * HID + lane];
                acc0 += __int_as_float(c0.y) * v0;
                acc1 += __int_as_float(c1.y) * v1;
                acc2 += __int_as_float(c2.y) * v2;
                acc3 += __int_as_float(c3.y) * v3;
                c0 = d0; c1 = d1; c2 = d2; c3 = d3;
                v0 = u0; v1 = u1; v2 = u2; v3 = u3;
            }
            acc0 += __int_as_float(c0.y) * v0;
            acc1 += __int_as_float(c1.y) * v1;
            acc2 += __int_as_float(c2.y) * v2;
            acc3 += __int_as_float(c3.y) * v3;
        }
        float acc = (acc0 + acc1) + (acc2 + acc3) + bias[lane];
        out[(size_t)row * HID + lane] = fmaxf(acc, 0.f);
    }
}

// one block (4 waves) per graph: mean+max pool over its node range, fused output dot
__global__ __launch_bounds__(256) void pool_kernel(const float* __restrict__ h,
                                                   const int* __restrict__ batch,
                                                   const float* __restrict__ Wout,
                                                   const float* __restrict__ bout,
                                                   float* __restrict__ d_out, int n) {
    __shared__ float ssum[4][64];
    __shared__ float smax[4][64];
    int g = blockIdx.x;
    int wave = threadIdx.x >> 6, j = threadIdx.x & 63;
    int lo = 0, hi = n;
    while (lo < hi) { int mid = (lo + hi) >> 1; if (batch[mid] < g) lo = mid + 1; else hi = mid; }
    int start = lo;
    hi = n;
    while (lo < hi) { int mid = (lo + hi) >> 1; if (batch[mid] < g + 1) lo = mid + 1; else hi = mid; }
    int end = lo;

    float sum = 0.f, mx = 0.f;   // h >= 0 post-relu; empty graph -> 0 per reference
    for (int i = start + wave; i < end; i += 4) {
        float v = h[(size_t)i * HID + j];
        sum += v;
        mx = fmaxf(mx, v);
    }
    ssum[wave][j] = sum;
    smax[wave][j] = mx;
    __syncthreads();
    if (wave == 0) {
        sum = (ssum[0][j] + ssum[1][j]) + (ssum[2][j] + ssum[3][j]);
        mx = fmaxf(fmaxf(smax[0][j], smax[1][j]), fmaxf(smax[2][j], smax[3][j]));
        float cnt = (float)(end - start);
        float mean = sum / fmaxf(cnt, 1.f);
        float* pooled = d_out + NUM_GRAPHS;
        pooled[(size_t)g * (2 * HID) + j] = mean;
        pooled[(size_t)g * (2 * HID) + HID + j] = mx;
        float c = mean * Wout[j] + mx * Wout[HID + j];
#pragma unroll
        for (int off = 32; off; off >>= 1) c += __shfl_down(c, off);
        if (j == 0) d_out[g] = c + bout[0];
    }
}

// ---------------- launch ----------------

extern "C" void kernel_launch(void* const* d_in, const int* in_sizes, int n_in,
                              void* d_out, int out_size, void* d_ws, size_t ws_size,
                              hipStream_t stream) {
    const float* x    = (const float*)d_in[0];
    const int*   edge = (const int*)d_in[1];
    const int*   batch= (const int*)d_in[2];
    const float* W1 = (const float*)d_in[3];  const float* b1 = (const float*)d_in[4];
    const float* W2 = (const float*)d_in[5];  const float* b2 = (const float*)d_in[6];
    const float* W3 = (const float*)d_in[7];  const float* b3 = (const float*)d_in[8];
    const float* W4 = (const float*)d_in[9];  const float* b4 = (const float*)d_in[10];
    const float* Wout = (const float*)d_in[11]; const float* bout = (const float*)d_in[12];
    float* out = (float*)d_out;

    const int N = N_NODES;
    const int E = in_sizes[1] / 2;
    const int* src = edge;
    const int* dst = edge + E;

    char* p = (char*)d_ws;
    auto alloc = [&](size_t bytes) -> char* {
        char* r = p;
        p += (bytes + 255) & ~(size_t)255;
        return r;
    };
    int*   deg      = (int*)alloc((size_t)N * 4);
    int*   row_ptr  = (int*)alloc((size_t)(N + 1) * 4);
    int*   row_fill = (int*)alloc((size_t)N * 4);
    int2*  cne      = (int2*)alloc((size_t)CNE_MAX * 8);
    float* dis      = (float*)alloc((size_t)N * 4);
    int*   bsum     = (int*)alloc(128 * 4);
    int*   boff     = (int*)alloc(128 * 4);
    float* tmp      = (float*)alloc((size_t)N * HID * 4);
    float* hA       = (float*)alloc((size_t)N * HID * 4);

    hipMemsetAsync(deg, 0, (size_t)N * 4, stream);
    hipMemsetAsync(cne, 0, (size_t)CNE_MAX * 8, stream);   // pad entries -> col 0, norm 0
    count_deg<<<(E + 255) / 256, 256, 0, stream>>>(dst, deg, E);
    compute_dis<<<(N + 255) / 256, 256, 0, stream>>>(deg, dis, N);

    int nb = (N + 1023) / 1024;  // 98
    scan1<<<nb, 256, 0, stream>>>(deg, row_ptr + 1, bsum, N);
    scan2<<<1, 128, 0, stream>>>(bsum, boff, nb);
    scan3<<<(N + 255) / 256, 256, 0, stream>>>(deg, row_ptr, row_fill, boff, N);
    scatter_edges<<<(E + 255) / 256, 256, 0, stream>>>(src, dst, dis, row_fill, cne, E);

    const int AGG_BLOCKS = 2048;

    gemm_rows<IN_DIM><<<1024, 256, 0, stream>>>(x, W1, tmp, N);
    aggregate<<<AGG_BLOCKS, 256, 0, stream>>>(tmp, dis, row_ptr, cne, b1, hA, N);
    gemm_rows<HID><<<2048, 256, 0, stream>>>(hA, W2, tmp, N);
    aggregate<<<AGG_BLOCKS, 256, 0, stream>>>(tmp, dis, row_ptr, cne, b2, hA, N);
    gemm_rows<HID><<<2048, 256, 0, stream>>>(hA, W3, tmp, N);
    aggregate<<<AGG_BLOCKS, 256, 0, stream>>>(tmp, dis, row_ptr, cne, b3, hA, N);
    gemm_rows<HID><<<2048, 256, 0, stream>>>(hA, W4, tmp, N);
    aggregate<<<AGG_BLOCKS, 256, 0, stream>>>(tmp, dis, row_ptr, cne, b4, hA, N);

    pool_kernel<<<NUM_GRAPHS, 256, 0, stream>>>(hA, batch, Wout, bout, out, N);
}